// Round 5
// baseline (67.834 us; speedup 1.0000x reference)
//
#include <hip/hip_runtime.h>

#define BB 32
#define AA 8400
#define NGT 64
#define NCLS 80
#define TOPK 13
#define SLOTS 4
#define CHUNK 256
#define NCHUNK 33   // ceil(8400/256)

// anchor center for flat index a (exact: (i+0.5)*stride, row-major y,x)
__device__ __forceinline__ void anchor_xy(int a, float& px, float& py) {
    if (a < 6400)      { int y = a / 80;          int x = a - 80 * y;  px = (x + 0.5f) * 8.0f;  py = (y + 0.5f) * 8.0f; }
    else if (a < 8000) { int r = a - 6400; int y = r / 40; int x = r - 40 * y; px = (x + 0.5f) * 16.0f; py = (y + 0.5f) * 16.0f; }
    else               { int r = a - 8000; int y = r / 20; int x = r - 20 * y; px = (x + 0.5f) * 32.0f; py = (y + 0.5f) * 32.0f; }
}

// One BLOCK (4 waves) per (b, n): candidates split 4-way across waves;
// per-wave top-13 via shfl_xor butterfly on packed (value, ~idx) u64 keys;
// wave 0 merges and writes the top-13 anchor list (16 ints, -1 padded).
__global__ __launch_bounds__(256) void k_topk(
    const float* __restrict__ pd_scores,
    const float4* __restrict__ pd_bboxes,
    const int* __restrict__ gt_labels,
    const float4* __restrict__ gt_bboxes,
    const float* __restrict__ mask_gt,
    int* __restrict__ list)
{
    __shared__ unsigned long long keys[4 * TOPK];
    int gid = blockIdx.x;                       // = b*64 + n
    int tid = threadIdx.x;
    int w = tid >> 6, lane = tid & 63;
    if (mask_gt[gid] <= 0.0f) {
        if (tid < 16) list[gid * 16 + tid] = -1;
        return;
    }
    int b = gid >> 6;
    float4 g = gt_bboxes[gid];
    int label = gt_labels[gid];
    float ga1 = (g.z - g.x) * (g.w - g.y);

    if (tid < 4 * TOPK) keys[tid] = 0;

    float va[SLOTS]; int ai[SLOTS]; int cnt = 0;
    #pragma unroll
    for (int j = 0; j < SLOTS; ++j) { va[j] = -1.0f; ai[j] = -1; }

#define SCAN_LEVEL(S, N, OFF)                                                   \
    {                                                                           \
        const float inv = 1.0f / (float)(S);                                    \
        int xlo = (int)floorf(g.x * inv - 0.5f); if (xlo < 0) xlo = 0;          \
        int xhi = (int)ceilf (g.z * inv - 0.5f); if (xhi > (N)-1) xhi = (N)-1;  \
        int ylo = (int)floorf(g.y * inv - 0.5f); if (ylo < 0) ylo = 0;          \
        int yhi = (int)ceilf (g.w * inv - 0.5f); if (yhi > (N)-1) yhi = (N)-1;  \
        int nx = xhi - xlo + 1, ny = yhi - ylo + 1;                             \
        int tot = (nx > 0 && ny > 0) ? nx * ny : 0;                             \
        for (int c = tid; c < tot; c += 256) {                                  \
            int yy = c / nx, xx = c - yy * nx;                                  \
            int gx = xlo + xx, gy = ylo + yy;                                   \
            int a = (OFF) + gy * (N) + gx;                                      \
            float px = (gx + 0.5f) * (float)(S), py = (gy + 0.5f) * (float)(S); \
            float dmin = fminf(fminf(px - g.x, py - g.y),                       \
                               fminf(g.z - px, g.w - py));                      \
            if (dmin > 1e-9f) {                                                 \
                float4 pb = pd_bboxes[b * AA + a];                              \
                float ltx = fmaxf(g.x, pb.x), lty = fmaxf(g.y, pb.y);           \
                float rbx = fminf(g.z, pb.z), rby = fminf(g.w, pb.w);           \
                float wd = fmaxf(rbx - ltx, 0.0f), hg = fmaxf(rby - lty, 0.0f); \
                float inter = wd * hg;                                          \
                float a2 = (pb.z - pb.x) * (pb.w - pb.y);                       \
                float iou = fmaxf(inter / (ga1 + a2 - inter + 1e-7f), 0.0f);    \
                float sc = pd_scores[(size_t)(b * AA + a) * NCLS + label];      \
                float i2 = iou * iou;                                           \
                float v = sc * (i2 * i2 * i2);                                  \
                if (v > 0.0f) {                                                 \
                    _Pragma("unroll")                                           \
                    for (int j = 0; j < SLOTS; ++j)                             \
                        if (j == cnt) { va[j] = v; ai[j] = a; }                 \
                    cnt++;                                                      \
                }                                                               \
            }                                                                   \
        }                                                                       \
    }

    SCAN_LEVEL(8, 80, 0)
    SCAN_LEVEL(16, 40, 6400)
    SCAN_LEVEL(32, 20, 8000)
#undef SCAN_LEVEL

    __syncthreads();   // keys[] init visible to all waves

    // per-wave top-13 extraction into LDS (descending; zeros beyond count)
    for (int k = 0; k < TOPK; ++k) {
        unsigned long long key = 0;
        #pragma unroll
        for (int j = 0; j < SLOTS; ++j)
            if (va[j] > 0.0f) {
                unsigned long long kk =
                    ((unsigned long long)__float_as_uint(va[j]) << 32)
                    | (unsigned)(0x7FFFFFFF - ai[j]);   // bigger = smaller idx
                key = kk > key ? kk : key;
            }
        #pragma unroll
        for (int off = 32; off; off >>= 1) {
            unsigned long long o = __shfl_xor(key, off);
            key = o > key ? o : key;
        }
        if (key == 0) break;
        if (lane == 0) keys[w * TOPK + k] = key;
        int wa = 0x7FFFFFFF - (int)(unsigned)(key & 0xFFFFFFFFull);
        #pragma unroll
        for (int j = 0; j < SLOTS; ++j) if (ai[j] == wa) va[j] = -1.0f;
    }

    __syncthreads();

    // wave 0 merges the 52 candidate keys (all distinct anchors) -> list
    if (w == 0) {
        unsigned long long mykey = (lane < 4 * TOPK) ? keys[lane] : 0;
        int kc = 0;
        for (int k = 0; k < TOPK; ++k) {
            unsigned long long best = mykey;
            #pragma unroll
            for (int off = 32; off; off >>= 1) {
                unsigned long long o = __shfl_xor(best, off);
                best = o > best ? o : best;
            }
            if (best == 0) break;
            if (lane == 0)
                list[gid * 16 + k] = 0x7FFFFFFF - (int)(unsigned)(best & 0xFFFFFFFFull);
            kc++;
            if (mykey == best) mykey = 0;
        }
        if (lane == 0)
            for (int k = kc; k < 16; ++k) list[gid * 16 + k] = -1;
    }
}

// One block per (batch b, 256-anchor chunk): rebuild selection mask in LDS
// from the batch's 64x16 list, resolve conflicts with an 8-wide branchless
// (prefetchable) gt loop, write bbox/fg and coalesced score rows.
__global__ __launch_bounds__(256) void k_out(
    const float* __restrict__ pd_scores,
    const float4* __restrict__ pd_bboxes,
    const int* __restrict__ gt_labels,
    const float4* __restrict__ gt_bboxes,
    const float* __restrict__ mask_gt,
    const int* __restrict__ list,
    float4* __restrict__ out_bbox,
    float* __restrict__ out_fg,
    float4* __restrict__ out_scores)
{
    __shared__ unsigned int s_lo[CHUNK], s_hi[CHUNK];
    __shared__ float4 s_gt[NGT];
    __shared__ int    s_glab[NGT];
    __shared__ float  s_gmsk[NGT];
    __shared__ float  s_pos[CHUNK];
    __shared__ int    s_alab[CHUNK];

    int bidx = blockIdx.x;
    int b = bidx / NCHUNK;
    int chunk = bidx - b * NCHUNK;
    int abase = chunk * CHUNK;
    int count = AA - abase; if (count > CHUNK) count = CHUNK;
    int tid = threadIdx.x;

    s_lo[tid] = 0; s_hi[tid] = 0;
    if (tid < NGT) {
        s_gt[tid]   = gt_bboxes[b * NGT + tid];
        s_glab[tid] = gt_labels[b * NGT + tid];
        s_gmsk[tid] = mask_gt[b * NGT + tid];
    }
    __syncthreads();

    // scatter the batch's selections that fall in this chunk into LDS mask
    const int* blist = list + b * NGT * 16;
    #pragma unroll
    for (int e = tid; e < NGT * 16; e += 256) {
        int a = blist[e];
        int rel = a - abase;
        if (a >= 0 && rel >= 0 && rel < count) {
            int n = e >> 4;
            if (n < 32) atomicOr(&s_lo[rel], 1u << n);
            else        atomicOr(&s_hi[rel], 1u << (n - 32));
        }
    }
    __syncthreads();

    if (tid < count) {
        int a = abase + tid;
        int idx = b * AA + a;
        unsigned long long m = ((unsigned long long)s_hi[tid] << 32) | s_lo[tid];
        float pos = 0.0f; int tgt = 0; int fg = 0;
        if (m) {
            float px, py; anchor_xy(a, px, py);
            float4 pb = pd_bboxes[idx];
            float a2 = (pb.z - pb.x) * (pb.w - pb.y);
            if (__popcll(m) == 1) {
                int n = __ffsll((unsigned long long)m) - 1;
                float4 g = s_gt[n];
                float ltx = fmaxf(g.x, pb.x), lty = fmaxf(g.y, pb.y);
                float rbx = fminf(g.z, pb.z), rby = fminf(g.w, pb.w);
                float wd = fmaxf(rbx - ltx, 0.0f), hg = fmaxf(rby - lty, 0.0f);
                float inter = wd * hg;
                float a1 = (g.z - g.x) * (g.w - g.y);
                float iou = fmaxf(inter / (a1 + a2 - inter + 1e-7f), 0.0f);
                float sc = pd_scores[(size_t)idx * NCLS + s_glab[n]];
                float i2 = iou * iou;
                pos = sc * (i2 * i2 * i2);
                tgt = n; fg = 1;
            } else {
                // conflict: keep selected gts whose metric equals the max over
                // ALL gts. 8-wide branchless batches -> independent score loads.
                float mmax = 0.0f; unsigned long long nb = 0;
                for (int j0 = 0; j0 < NGT; j0 += 8) {
                    float v[8];
                    #pragma unroll
                    for (int j = 0; j < 8; ++j) {
                        int n = j0 + j;
                        float4 g = s_gt[n];
                        float sc = pd_scores[(size_t)idx * NCLS + s_glab[n]];
                        float dmin = fminf(fminf(px - g.x, py - g.y),
                                           fminf(g.z - px, g.w - py));
                        float ltx = fmaxf(g.x, pb.x), lty = fmaxf(g.y, pb.y);
                        float rbx = fminf(g.z, pb.z), rby = fminf(g.w, pb.w);
                        float wd = fmaxf(rbx - ltx, 0.0f), hg = fmaxf(rby - lty, 0.0f);
                        float inter = wd * hg;
                        float a1 = (g.z - g.x) * (g.w - g.y);
                        float iou = fmaxf(inter / (a1 + a2 - inter + 1e-7f), 0.0f);
                        float i2 = iou * iou;
                        bool ok = (s_gmsk[n] > 0.0f) && (dmin > 1e-9f);
                        v[j] = ok ? sc * (i2 * i2 * i2) : 0.0f;
                    }
                    #pragma unroll
                    for (int j = 0; j < 8; ++j) {
                        int n = j0 + j;
                        float vv = v[j];
                        if (vv > mmax) { mmax = vv; nb = m & (1ull << n); }
                        else if (vv == mmax && vv > 0.0f) nb |= m & (1ull << n);
                    }
                }
                if (nb) { tgt = __ffsll(nb) - 1; pos = mmax; fg = 1; }
            }
        }
        out_bbox[idx] = s_gt[tgt];
        out_fg[idx] = fg ? 1.0f : 0.0f;
        s_pos[tid] = pos;
        s_alab[tid] = s_glab[tgt];
    }
    __syncthreads();

    // count anchors * 20 float4, block-linear -> fully coalesced
    float4* dst = out_scores + (size_t)(b * AA + abase) * (NCLS / 4);
    int total = count * (NCLS / 4);
    for (int ci = tid; ci < total; ci += 256) {
        int an = ci / (NCLS / 4);
        int c0 = (ci - an * (NCLS / 4)) * 4;
        float p = s_pos[an];
        int lb = s_alab[an];
        float4 r = make_float4(0.f, 0.f, 0.f, 0.f);
        if (p != 0.0f) {
            if (lb == c0)     r.x = p;
            if (lb == c0 + 1) r.y = p;
            if (lb == c0 + 2) r.z = p;
            if (lb == c0 + 3) r.w = p;
        }
        dst[ci] = r;
    }
}

extern "C" void kernel_launch(void* const* d_in, const int* in_sizes, int n_in,
                              void* d_out, int out_size, void* d_ws, size_t ws_size,
                              hipStream_t stream) {
    const float*  pd_scores = (const float*) d_in[0];
    const float4* pd_bboxes = (const float4*)d_in[1];
    const int*    gt_labels = (const int*)   d_in[3];
    const float4* gt_bboxes = (const float4*)d_in[4];
    const float*  mask_gt   = (const float*) d_in[5];

    float* out = (float*)d_out;
    float4* out_bbox   = (float4*)out;                         // B*A*4 floats
    float4* out_scores = (float4*)(out + (size_t)BB * AA * 4); // B*A*NC floats
    float*  out_fg     = out + (size_t)BB * AA * 4 + (size_t)BB * AA * NCLS;

    int* list = (int*)d_ws;   // BB*NGT*16 ints, fully rewritten every call

    k_topk<<<BB * NGT, 256, 0, stream>>>(pd_scores, pd_bboxes,
                                         gt_labels, gt_bboxes, mask_gt, list);

    k_out<<<BB * NCHUNK, 256, 0, stream>>>(
        pd_scores, pd_bboxes, gt_labels, gt_bboxes, mask_gt, list,
        out_bbox, out_fg, out_scores);
}